// Round 14
// baseline (397.666 us; speedup 1.0000x reference)
//
#include <hip/hip_runtime.h>
#include <cstdint>
#include <cstddef>

// Problem constants (match the JAX reference)
#define MM 2
#define DD 128
#define RR 8
#define NN0 8192
#define LLV 32
#define KK 4096
#define NTHAX 1000
#define NTOT (NN0 + LLV*KK)     // 139264
#define NB 16                   // nodes per chunk (MFMA M-tile)
#define CHN16 264               // max chunks/level: ceil((4096 + 8*15)/16) = 264
#define EBLK 2048               // eval blocks
#define TBLK 64                 // totals blocks

typedef short bf16x8 __attribute__((ext_vector_type(8)));   // 8 bf16 (4 VGPRs)
typedef float f32x4  __attribute__((ext_vector_type(4)));

__device__ __forceinline__ unsigned short f2bf(float f){
  union { float f; uint32_t u; } x; x.f = f;
  uint32_t u = x.u + 0x7FFFu + ((x.u >> 16) & 1u);   // RNE
  return (unsigned short)(u >> 16);
}
__device__ __forceinline__ float bf2f(unsigned short h){
  union { uint32_t u; float f; } x; x.u = ((uint32_t)h) << 16; return x.f;
}

// ---------------------------------------------------------------------------
// Preprocess: per level, counting-sort node indices by rule into NB-padded
// chunks so each level-kernel block handles exactly one rule.
// ---------------------------------------------------------------------------
__global__ void prep_kernel(const int* __restrict__ rule_ids,
                            int* __restrict__ chunk_nodes,   // [LLV][CHN16][NB]
                            int* __restrict__ chunk_rule,    // [LLV][CHN16]
                            int* __restrict__ nchunks)       // [LLV]
{
  const int l = blockIdx.x, t = threadIdx.x;
  __shared__ int cnt[RR], start[RR], fill[RR];
  if (t < RR){ cnt[t] = 0; fill[t] = 0; }
  __syncthreads();
  for (int k = t; k < KK; k += blockDim.x) atomicAdd(&cnt[rule_ids[l*KK + k]], 1);
  __syncthreads();
  if (t == 0){
    int s = 0;
    for (int r = 0; r < RR; ++r){
      start[r] = s;
      int pad = (cnt[r] + NB - 1)/NB*NB;
      for (int c = s/NB; c < (s+pad)/NB; ++c) chunk_rule[l*CHN16 + c] = r;
      s += pad;
    }
    nchunks[l] = s/NB;
  }
  __syncthreads();
  for (int i = t; i < CHN16*NB; i += blockDim.x) chunk_nodes[l*CHN16*NB + i] = -1;
  __syncthreads();
  for (int k = t; k < KK; k += blockDim.x){
    int r = rule_ids[l*KK + k];
    int p = start[r] + atomicAdd(&fill[r], 1);   // LDS atomics only
    chunk_nodes[l*CHN16*NB + p] = k;
  }
}

// ---------------------------------------------------------------------------
// Weight conversion fp32 -> bf16 in MFMA-B-fragment-native layout (both W1,W2):
// Wt[(mr*(K/8) + kb)*DD*8 + e*8 + j] = bf16(W[(mr*K + kb*8+j)*DD + e])
// ---------------------------------------------------------------------------
__global__ void convw_kernel(const float* __restrict__ W1, const float* __restrict__ W2,
                             unsigned short* __restrict__ W1t, unsigned short* __restrict__ W2t)
{
  int idx = blockIdx.x*blockDim.x + threadIdx.x;
  const int N1 = MM*RR*256*DD;
  const int N2 = MM*RR*128*DD;
  if (idx < N1){
    int e = idx & 127;
    int k = (idx >> 7) & 255;        // K=256
    int mr = idx >> 15;
    float v = W1[((size_t)mr*256 + k)*DD + e];
    W1t[((size_t)mr*32 + (k >> 3))*DD*8 + e*8 + (k & 7)] = f2bf(v);
  } else {
    idx -= N1;
    if (idx >= N2) return;
    int e = idx & 127;
    int k = (idx >> 7) & 127;        // K=128
    int mr = idx >> 14;
    float v = W2[((size_t)mr*128 + k)*DD + e];
    W2t[((size_t)mr*16 + (k >> 3))*DD*8 + e*8 + (k & 7)] = f2bf(v);
  }
}

// ---------------------------------------------------------------------------
// Init nodes (bf16 store): store[i][m][d] = bf16(emb * sigmoid(s*w + b))
// ---------------------------------------------------------------------------
__global__ void init_kernel(const int* __restrict__ thax_ids, const int* __restrict__ sine_ids,
                            const float* __restrict__ thax_table,
                            const float* __restrict__ sine_w, const float* __restrict__ sine_b,
                            unsigned short* __restrict__ store)
{
  int idx = blockIdx.x*blockDim.x + threadIdx.x;    // over NN0*MM*DD
  if (idx >= NN0*MM*DD) return;
  int i = idx >> 8;            // node
  int md = idx & 255;
  int m = md >> 7, d = md & 127;
  float emb = thax_table[((size_t)m*NTHAX + thax_ids[i])*DD + d];
  float s = (float)sine_ids[i];
  float z = s*sine_w[m*DD + d] + sine_b[m*DD + d];
  float sig = 1.f/(1.f + expf(-z));
  store[idx] = f2bf(emb*sig);
}

// ---------------------------------------------------------------------------
// Totals: per-block partial sums of pos/neg (no atomics)
// ---------------------------------------------------------------------------
__global__ void totals_kernel(const float* __restrict__ pos, const float* __restrict__ neg,
                              float* __restrict__ pt)
{
  __shared__ float ts[4][2];
  const int t = threadIdx.x, lane = t & 63;
  float sp = 0.f, sn = 0.f;
  for (int n = blockIdx.x*blockDim.x + t; n < NTOT; n += gridDim.x*blockDim.x){
    sp += pos[n]; sn += neg[n];
  }
  #pragma unroll
  for (int s = 1; s < 64; s <<= 1){ sp += __shfl_xor(sp, s, 64); sn += __shfl_xor(sn, s, 64); }
  if (lane == 0){ ts[t>>6][0] = sp; ts[t>>6][1] = sn; }
  __syncthreads();
  if (t < 2) pt[t*TBLK + blockIdx.x] = ts[0][t] + ts[1][t] + ts[2][t] + ts[3][t];
}

// ---------------------------------------------------------------------------
// One level via MFMA, NO X staging: A-fragments for layer 1 are loaded
// DIRECTLY from global (lane lr reads 16B of row par[lr][k>>7]).  The 4
// waves read the same rows at different e-slices -> L1 broadcast.  This
// removes a global->LDS round-trip + 1 barrier from the critical path.
// H stays in LDS (swizzled) for layer 2's k-major re-read.
// XCD-pair swizzle keeps (c,m=0)/(c,m=1) on one XCD (shared parent lines).
// ---------------------------------------------------------------------------
__global__ __launch_bounds__(256, 4) void level_kernel(
    unsigned short* __restrict__ store,
    const int* __restrict__ parents,      // [LLV][KK][2]
    const int* __restrict__ chunk_nodes,  // [LLV][CHN16][NB]
    const int* __restrict__ chunk_rule,   // [LLV][CHN16]
    const int* __restrict__ nchunks,      // [LLV]
    const unsigned short* __restrict__ W1t, const float* __restrict__ b1,
    const unsigned short* __restrict__ W2t, const float* __restrict__ b2,
    int level)
{
  const int bid = blockIdx.x;
  const int c = (bid >> 4)*8 + (bid & 7);       // XCD-pair swizzle
  const int m = (bid >> 3) & 1;
  if (c >= nchunks[level]) return;
  const int r = chunk_rule[level*CHN16 + c];

  __shared__ __align__(16) unsigned short Hs[16*128];  // 4KB bf16, swizzled rows of 256B
  __shared__ int nd[NB];
  __shared__ int par[NB][2];

  const int t  = threadIdx.x;
  const int w  = t >> 6;        // wave -> e-slice
  const int l  = t & 63;
  const int lr = l & 15;        // row (A) / col (B,D) within tile
  const int lg = l >> 4;        // k-group (A,B) / row-group (D)

  if (t < NB){
    int node = chunk_nodes[(level*CHN16 + c)*NB + t];
    nd[t] = node;
    const int* parL = parents + (size_t)level*KK*2;
    int p0 = 0, p1 = 0;
    if (node >= 0){ p0 = parL[node*2]; p1 = parL[node*2 + 1]; }
    par[t][0] = p0; par[t][1] = p1;
  }
  __syncthreads();

  // per-lane A-row bases (both parents), loop-invariant
  const unsigned short* arow0 = store + (size_t)par[lr][0]*(MM*DD) + m*DD;
  const unsigned short* arow1 = store + (size_t)par[lr][1]*(MM*DD) + m*DD;

  // ---------------- Layer 1: C[16x32slice] = X[16x256] * W1 ----------------
  const unsigned short* W1p = W1t + (size_t)(m*RR + r)*(256/8)*DD*8;
  f32x4 acc0 = {0.f,0.f,0.f,0.f}, acc1 = {0.f,0.f,0.f,0.f};
  #pragma unroll
  for (int s = 0; s < 8; ++s){          // k = s*32 + lg*8
    int k = s*32 + lg*8;
    const unsigned short* ap = ((k & 128) ? arow1 : arow0) + (k & 127);
    bf16x8 a = *(const bf16x8*)ap;
    const unsigned short* bp = W1p + ((size_t)(s*4 + lg)*DD + w*32 + lr)*8;
    bf16x8 bf0 = *(const bf16x8*)bp;
    bf16x8 bf1 = *(const bf16x8*)(bp + 16*8);
    acc0 = __builtin_amdgcn_mfma_f32_16x16x32_bf16(a, bf0, acc0, 0, 0, 0);
    acc1 = __builtin_amdgcn_mfma_f32_16x16x32_bf16(a, bf1, acc1, 0, 0, 0);
  }

  // bias + relu -> Hs (bf16, swizzled).  D: col=lr(+e-slice), row=lg*4+reg.
  {
    const float* b1v = b1 + (m*RR + r)*DD;
    int col0 = w*32 + lr;
    float bb0 = b1v[col0], bb1 = b1v[col0 + 16];
    #pragma unroll
    for (int reg = 0; reg < 4; ++reg){
      int row = lg*4 + reg;
      float h0 = fmaxf(acc0[reg] + bb0, 0.f);
      float h1 = fmaxf(acc1[reg] + bb1, 0.f);
      int sw = (row & 7) << 4;
      *(unsigned short*)((char*)Hs + row*256 + ((col0*2) ^ sw))        = f2bf(h0);
      *(unsigned short*)((char*)Hs + row*256 + (((col0 + 16)*2) ^ sw)) = f2bf(h1);
    }
  }
  __syncthreads();

  // ---------------- Layer 2: C[16x32slice] = H[16x128] * W2 ----------------
  const unsigned short* W2p = W2t + (size_t)(m*RR + r)*(128/8)*DD*8;
  acc0 = (f32x4){0.f,0.f,0.f,0.f};
  acc1 = (f32x4){0.f,0.f,0.f,0.f};
  #pragma unroll
  for (int s = 0; s < 4; ++s){          // k = s*32
    int ab = lr*256 + ((s*64 + lg*16) ^ ((lr & 7) << 4));
    bf16x8 a = *(const bf16x8*)((const char*)Hs + ab);
    const unsigned short* bp = W2p + ((size_t)(s*4 + lg)*DD + w*32 + lr)*8;
    bf16x8 bf0 = *(const bf16x8*)bp;
    bf16x8 bf1 = *(const bf16x8*)(bp + 16*8);
    acc0 = __builtin_amdgcn_mfma_f32_16x16x32_bf16(a, bf0, acc0, 0, 0, 0);
    acc1 = __builtin_amdgcn_mfma_f32_16x16x32_bf16(a, bf1, acc1, 0, 0, 0);
  }

  // epilogue: + b2, write bf16 rows of store
  {
    const float* b2v = b2 + (m*RR + r)*DD;
    const size_t obase = (size_t)NN0 + (size_t)level*KK;
    int col0 = w*32 + lr;
    float bb0 = b2v[col0], bb1 = b2v[col0 + 16];
    #pragma unroll
    for (int reg = 0; reg < 4; ++reg){
      int row = lg*4 + reg;
      int node = nd[row];
      if (node >= 0){
        unsigned short* op = store + (obase + node)*(MM*DD) + m*DD;
        op[col0]      = f2bf(acc0[reg] + bb0);
        op[col0 + 16] = f2bf(acc1[reg] + bb1);
      }
    }
  }
}

// ---------------------------------------------------------------------------
// Eval (bf16 store): wave-per-node dot with w_eval, stable BCE.
// Per-block partials (NO atomics): pe[c][blk], c = q*2 + m,
// q: 0=A (pw part), 1=B, 2=posOK, 3=negOK.  loss = pw*A + B in finish.
// ---------------------------------------------------------------------------
__global__ void eval_kernel(const unsigned short* __restrict__ store,
                            const float* __restrict__ pos_cnt, const float* __restrict__ neg_cnt,
                            const float* __restrict__ w_eval, const float* __restrict__ b_eval,
                            float* __restrict__ pe)
{
  __shared__ float part[4][2][4];      // [wave][m][q]
  const int t = threadIdx.x, lane = t & 63;
  const int gw = blockIdx.x*(blockDim.x >> 6) + (t >> 6);
  const int nw = gridDim.x*(blockDim.x >> 6);
  float4 wv = *(const float4*)&w_eval[4*lane];          // lanes 0-31 -> m=0, 32-63 -> m=1
  const int m = (lane >= 32) ? 1 : 0;
  const float be = b_eval[m];
  float A = 0.f, B = 0.f, pOK = 0.f, nOK = 0.f;
  for (int n = gw; n < NTOT; n += nw){
    ushort4 v4 = *(const ushort4*)&store[(size_t)n*(MM*DD) + 4*lane];
    float p = bf2f(v4.x)*wv.x + bf2f(v4.y)*wv.y + bf2f(v4.z)*wv.z + bf2f(v4.w)*wv.w;
    #pragma unroll
    for (int s = 1; s < 32; s <<= 1) p += __shfl_xor(p, s, 64);   // reduce within each m-half
    const float val = p + be;
    if ((lane & 31) == 0){
      const float pc = pos_cnt[n], nc = neg_cnt[n];
      const float cnt = pc + nc;
      if (cnt > 0.f){
        float gold = pc / fmaxf(cnt, 1.f);
        float e = log1pf(expf(-fabsf(val)));
        float sp_pos = e + fmaxf(val, 0.f);     // softplus(val)
        float sp_neg = e + fmaxf(-val, 0.f);    // softplus(-val)
        A += cnt * gold * sp_neg;
        B += cnt * (1.f - gold) * sp_pos;
      }
      pOK += (val >= 0.f) ? pc : 0.f;
      nOK += (val <  0.f) ? nc : 0.f;
    }
  }
  if ((lane & 31) == 0){
    int wv2 = t >> 6;
    part[wv2][m][0] = A; part[wv2][m][1] = B; part[wv2][m][2] = pOK; part[wv2][m][3] = nOK;
  }
  __syncthreads();
  if (t < 8){
    int q = t >> 1, mm = t & 1;
    float s = part[0][mm][q] + part[1][mm][q] + part[2][mm][q] + part[3][mm][q];
    pe[t*EBLK + blockIdx.x] = s;
  }
}

// ---------------------------------------------------------------------------
// Finish: reduce totals + eval partials, compute pw, write 6 outputs.
// ---------------------------------------------------------------------------
__global__ void finish_kernel(const float* __restrict__ pt, const float* __restrict__ pe,
                              float* __restrict__ out)
{
  __shared__ float acc8[8];
  __shared__ float tt[2];
  const int t = threadIdx.x;             // 256
  if (t < 64){                           // totals: comp c = t>>5
    int c = t >> 5, l = t & 31;
    float s = pt[c*TBLK + l] + pt[c*TBLK + l + 32];
    #pragma unroll
    for (int d = 1; d < 32; d <<= 1) s += __shfl_xor(s, d, 64);
    if (l == 0) tt[c] = s;
  }
  {
    int comp = t >> 5, l = t & 31;
    float s = 0.f;
    for (int i = 0; i < EBLK/32; ++i) s += pe[comp*EBLK + i*32 + l];
    #pragma unroll
    for (int d = 1; d < 32; d <<= 1) s += __shfl_xor(s, d, 64);
    if (l == 0) acc8[comp] = s;
  }
  __syncthreads();
  if (t < 2){                            // m = t
    float tp = tt[0], tn = tt[1];
    float pw = (tp > 0.f) ? (tn / fmaxf(tp, 1.f)) : 1.f;   // POS_WEIGHT_EXTRA = 1
    out[t]     = pw*acc8[0 + t] + acc8[2 + t];
    out[2 + t] = acc8[4 + t];
    out[4 + t] = acc8[6 + t];
  }
}

// ---------------------------------------------------------------------------
extern "C" void kernel_launch(void* const* d_in, const int* in_sizes, int n_in,
                              void* d_out, int out_size, void* d_ws, size_t ws_size,
                              hipStream_t stream)
{
  const int*   thax_ids   = (const int*)d_in[0];
  const int*   sine_ids   = (const int*)d_in[1];
  const int*   parents    = (const int*)d_in[2];
  const int*   rule_ids   = (const int*)d_in[3];
  const float* pos_cnt    = (const float*)d_in[4];
  const float* neg_cnt    = (const float*)d_in[5];
  const float* thax_table = (const float*)d_in[6];
  const float* sine_w     = (const float*)d_in[7];
  const float* sine_b     = (const float*)d_in[8];
  const float* W1         = (const float*)d_in[9];
  const float* b1         = (const float*)d_in[10];
  const float* W2         = (const float*)d_in[11];
  const float* b2         = (const float*)d_in[12];
  const float* w_eval     = (const float*)d_in[13];
  const float* b_eval     = (const float*)d_in[14];

  char* ws = (char*)d_ws;
  unsigned short* store = (unsigned short*)ws;
  size_t off = (size_t)NTOT*MM*DD*sizeof(unsigned short);   // 71.3 MB
  off = (off + 15) & ~(size_t)15;
  int* chunk_nodes = (int*)(ws + off); off += (size_t)LLV*CHN16*NB*sizeof(int);
  int* chunk_rule  = (int*)(ws + off); off += (size_t)LLV*CHN16*sizeof(int);
  int* nchunks     = (int*)(ws + off); off += (size_t)LLV*sizeof(int);
  float* pt        = (float*)(ws + off); off += (size_t)2*TBLK*sizeof(float);
  float* pe        = (float*)(ws + off); off += (size_t)8*EBLK*sizeof(float);
  off = (off + 15) & ~(size_t)15;
  unsigned short* W1t = (unsigned short*)(ws + off); off += (size_t)MM*RR*256*DD*sizeof(unsigned short);
  unsigned short* W2t = (unsigned short*)(ws + off); off += (size_t)MM*RR*128*DD*sizeof(unsigned short);

  prep_kernel<<<LLV, 256, 0, stream>>>(rule_ids, chunk_nodes, chunk_rule, nchunks);
  convw_kernel<<<(MM*RR*(256+128)*DD + 255)/256, 256, 0, stream>>>(W1, W2, W1t, W2t);
  init_kernel<<<(NN0*MM*DD + 255)/256, 256, 0, stream>>>(thax_ids, sine_ids, thax_table,
                                                         sine_w, sine_b, store);
  totals_kernel<<<TBLK, 256, 0, stream>>>(pos_cnt, neg_cnt, pt);

  for (int l = 0; l < LLV; ++l)
    level_kernel<<<CHN16*2, 256, 0, stream>>>(store, parents, chunk_nodes, chunk_rule,
                                              nchunks, W1t, b1, W2t, b2, l);

  eval_kernel<<<EBLK, 256, 0, stream>>>(store, pos_cnt, neg_cnt, w_eval, b_eval, pe);
  finish_kernel<<<1, 256, 0, stream>>>(pt, pe, (float*)d_out);
}

// Round 15
// 371.420 us; speedup vs baseline: 1.0707x; 1.0707x over previous
//
#include <hip/hip_runtime.h>
#include <cstdint>
#include <cstddef>

// Problem constants (match the JAX reference)
#define MM 2
#define DD 128
#define RR 8
#define NN0 8192
#define LLV 32
#define KK 4096
#define NTHAX 1000
#define NTOT (NN0 + LLV*KK)     // 139264
#define NB 16                   // nodes per chunk (MFMA M-tile)
#define CHN16 264               // max chunks/level: ceil((4096 + 8*15)/16) = 264
#define EBLK 2048               // eval blocks

typedef short bf16x8 __attribute__((ext_vector_type(8)));   // 8 bf16 (4 VGPRs)
typedef float f32x4  __attribute__((ext_vector_type(4)));

__device__ __forceinline__ unsigned short f2bf(float f){
  union { float f; uint32_t u; } x; x.f = f;
  uint32_t u = x.u + 0x7FFFu + ((x.u >> 16) & 1u);   // RNE
  return (unsigned short)(u >> 16);
}
__device__ __forceinline__ float bf2f(unsigned short h){
  union { uint32_t u; float f; } x; x.u = ((uint32_t)h) << 16; return x.f;
}

// ---------------------------------------------------------------------------
// Preprocess: per level, counting-sort node indices by rule into NB-padded
// chunks so each level-kernel block handles exactly one rule.
// ---------------------------------------------------------------------------
__global__ void prep_kernel(const int* __restrict__ rule_ids,
                            int* __restrict__ chunk_nodes,   // [LLV][CHN16][NB]
                            int* __restrict__ chunk_rule,    // [LLV][CHN16]
                            int* __restrict__ nchunks)       // [LLV]
{
  const int l = blockIdx.x, t = threadIdx.x;
  __shared__ int cnt[RR], start[RR], fill[RR];
  if (t < RR){ cnt[t] = 0; fill[t] = 0; }
  __syncthreads();
  for (int k = t; k < KK; k += blockDim.x) atomicAdd(&cnt[rule_ids[l*KK + k]], 1);
  __syncthreads();
  if (t == 0){
    int s = 0;
    for (int r = 0; r < RR; ++r){
      start[r] = s;
      int pad = (cnt[r] + NB - 1)/NB*NB;
      for (int c = s/NB; c < (s+pad)/NB; ++c) chunk_rule[l*CHN16 + c] = r;
      s += pad;
    }
    nchunks[l] = s/NB;
  }
  __syncthreads();
  for (int i = t; i < CHN16*NB; i += blockDim.x) chunk_nodes[l*CHN16*NB + i] = -1;
  __syncthreads();
  for (int k = t; k < KK; k += blockDim.x){
    int r = rule_ids[l*KK + k];
    int p = start[r] + atomicAdd(&fill[r], 1);   // LDS atomics only
    chunk_nodes[l*CHN16*NB + p] = k;
  }
}

// ---------------------------------------------------------------------------
// Weight conversion fp32 -> bf16 in MFMA-B-fragment-native layout (both W1,W2):
// Wt[(mr*(K/8) + kb)*DD*8 + e*8 + j] = bf16(W[(mr*K + kb*8+j)*DD + e])
// ---------------------------------------------------------------------------
__global__ void convw_kernel(const float* __restrict__ W1, const float* __restrict__ W2,
                             unsigned short* __restrict__ W1t, unsigned short* __restrict__ W2t)
{
  int idx = blockIdx.x*blockDim.x + threadIdx.x;
  const int N1 = MM*RR*256*DD;
  const int N2 = MM*RR*128*DD;
  if (idx < N1){
    int e = idx & 127;
    int k = (idx >> 7) & 255;        // K=256
    int mr = idx >> 15;
    float v = W1[((size_t)mr*256 + k)*DD + e];
    W1t[((size_t)mr*32 + (k >> 3))*DD*8 + e*8 + (k & 7)] = f2bf(v);
  } else {
    idx -= N1;
    if (idx >= N2) return;
    int e = idx & 127;
    int k = (idx >> 7) & 127;        // K=128
    int mr = idx >> 14;
    float v = W2[((size_t)mr*128 + k)*DD + e];
    W2t[((size_t)mr*16 + (k >> 3))*DD*8 + e*8 + (k & 7)] = f2bf(v);
  }
}

// ---------------------------------------------------------------------------
// Init nodes (bf16 store): store[i][m][d] = bf16(emb * sigmoid(s*w + b))
// ---------------------------------------------------------------------------
__global__ void init_kernel(const int* __restrict__ thax_ids, const int* __restrict__ sine_ids,
                            const float* __restrict__ thax_table,
                            const float* __restrict__ sine_w, const float* __restrict__ sine_b,
                            unsigned short* __restrict__ store)
{
  int idx = blockIdx.x*blockDim.x + threadIdx.x;    // over NN0*MM*DD
  if (idx >= NN0*MM*DD) return;
  int i = idx >> 8;            // node
  int md = idx & 255;
  int m = md >> 7, d = md & 127;
  float emb = thax_table[((size_t)m*NTHAX + thax_ids[i])*DD + d];
  float s = (float)sine_ids[i];
  float z = s*sine_w[m*DD + d] + sine_b[m*DD + d];
  float sig = 1.f/(1.f + expf(-z));
  store[idx] = f2bf(emb*sig);
}

// ---------------------------------------------------------------------------
// One level via MFMA (round-13 proven structure, minus barrier #1):
// block = (chunk of 16 same-rule nodes, m) via XCD-pair swizzle.
// chunk_nodes/parents are loaded per-thread (wave-uniform -> L1 broadcast)
// instead of via an LDS stage + barrier.  X staged coalesced into swizzled
// LDS as bf16; 4 waves; wave w owns e-slice [w*32, w*32+32); fp32 accumulate.
// ---------------------------------------------------------------------------
__global__ __launch_bounds__(256, 4) void level_kernel(
    unsigned short* __restrict__ store,
    const int* __restrict__ parents,      // [LLV][KK][2]
    const int* __restrict__ chunk_nodes,  // [LLV][CHN16][NB]
    const int* __restrict__ chunk_rule,   // [LLV][CHN16]
    const int* __restrict__ nchunks,      // [LLV]
    const unsigned short* __restrict__ W1t, const float* __restrict__ b1,
    const unsigned short* __restrict__ W2t, const float* __restrict__ b2,
    int level)
{
  const int bid = blockIdx.x;
  const int c = (bid >> 4)*8 + (bid & 7);       // XCD-pair swizzle
  const int m = (bid >> 3) & 1;
  if (c >= nchunks[level]) return;
  const int r = chunk_rule[level*CHN16 + c];

  __shared__ __align__(16) unsigned short Xs[16*256];  // 8KB bf16, swizzled rows of 512B
  __shared__ __align__(16) unsigned short Hs[16*128];  // 4KB bf16, swizzled rows of 256B

  const int t  = threadIdx.x;
  const int w  = t >> 6;        // wave -> e-slice
  const int l  = t & 63;
  const int lr = l & 15;        // row (A) / col (B,D) within tile
  const int lg = l >> 4;        // k-group (A,B) / row-group (D)

  const int* cn = chunk_nodes + (size_t)(level*CHN16 + c)*NB;
  const int* parL = parents + (size_t)level*KK*2;

  // ---- Stage X: per-thread node/parent lookup (L1-broadcast), then
  //      coalesced ushort4 gather, swizzled LDS write ----
  #pragma unroll
  for (int q4 = 0; q4 < 4; ++q4){
    int q = q4*256 + t;                 // 0..1023
    int n = q >> 6, dq = q & 63;        // dq = ushort4 index within 256-bf16 row
    int node = cn[n];                   // wave-uniform -> broadcast
    int p = (node >= 0) ? parL[node*2 + (dq >> 5)] : 0;
    ushort4 v = *(const ushort4*)(store + (size_t)p*(MM*DD) + m*DD + (dq & 31)*4);
    int addr = n*512 + ((dq*8) ^ ((n & 7) << 4));
    *(ushort4*)((char*)Xs + addr) = v;
  }
  __syncthreads();

  // ---------------- Layer 1: C[16x32slice] = X[16x256] * W1 ----------------
  const unsigned short* W1p = W1t + (size_t)(m*RR + r)*(256/8)*DD*8;
  f32x4 acc0 = {0.f,0.f,0.f,0.f}, acc1 = {0.f,0.f,0.f,0.f};
  #pragma unroll
  for (int s = 0; s < 8; ++s){          // k = s*32
    int ab = lr*512 + ((s*64 + lg*16) ^ ((lr & 7) << 4));
    bf16x8 a = *(const bf16x8*)((const char*)Xs + ab);
    const unsigned short* bp = W1p + ((size_t)(s*4 + lg)*DD + w*32 + lr)*8;
    bf16x8 bf0 = *(const bf16x8*)bp;
    bf16x8 bf1 = *(const bf16x8*)(bp + 16*8);
    acc0 = __builtin_amdgcn_mfma_f32_16x16x32_bf16(a, bf0, acc0, 0, 0, 0);
    acc1 = __builtin_amdgcn_mfma_f32_16x16x32_bf16(a, bf1, acc1, 0, 0, 0);
  }

  // bias + relu -> Hs (bf16, swizzled).  D: col=lr(+e-slice), row=lg*4+reg.
  {
    const float* b1v = b1 + (m*RR + r)*DD;
    int col0 = w*32 + lr;
    float bb0 = b1v[col0], bb1 = b1v[col0 + 16];
    #pragma unroll
    for (int reg = 0; reg < 4; ++reg){
      int row = lg*4 + reg;
      float h0 = fmaxf(acc0[reg] + bb0, 0.f);
      float h1 = fmaxf(acc1[reg] + bb1, 0.f);
      int sw = (row & 7) << 4;
      *(unsigned short*)((char*)Hs + row*256 + ((col0*2) ^ sw))        = f2bf(h0);
      *(unsigned short*)((char*)Hs + row*256 + (((col0 + 16)*2) ^ sw)) = f2bf(h1);
    }
  }
  __syncthreads();

  // ---------------- Layer 2: C[16x32slice] = H[16x128] * W2 ----------------
  const unsigned short* W2p = W2t + (size_t)(m*RR + r)*(128/8)*DD*8;
  acc0 = (f32x4){0.f,0.f,0.f,0.f};
  acc1 = (f32x4){0.f,0.f,0.f,0.f};
  #pragma unroll
  for (int s = 0; s < 4; ++s){          // k = s*32
    int ab = lr*256 + ((s*64 + lg*16) ^ ((lr & 7) << 4));
    bf16x8 a = *(const bf16x8*)((const char*)Hs + ab);
    const unsigned short* bp = W2p + ((size_t)(s*4 + lg)*DD + w*32 + lr)*8;
    bf16x8 bf0 = *(const bf16x8*)bp;
    bf16x8 bf1 = *(const bf16x8*)(bp + 16*8);
    acc0 = __builtin_amdgcn_mfma_f32_16x16x32_bf16(a, bf0, acc0, 0, 0, 0);
    acc1 = __builtin_amdgcn_mfma_f32_16x16x32_bf16(a, bf1, acc1, 0, 0, 0);
  }

  // epilogue: + b2, write bf16 rows of store (node via broadcast load)
  {
    const float* b2v = b2 + (m*RR + r)*DD;
    const size_t obase = (size_t)NN0 + (size_t)level*KK;
    int col0 = w*32 + lr;
    float bb0 = b2v[col0], bb1 = b2v[col0 + 16];
    #pragma unroll
    for (int reg = 0; reg < 4; ++reg){
      int row = lg*4 + reg;
      int node = cn[row];               // wave-uniform within 16-lane groups
      if (node >= 0){
        unsigned short* op = store + (obase + node)*(MM*DD) + m*DD;
        op[col0]      = f2bf(acc0[reg] + bb0);
        op[col0 + 16] = f2bf(acc1[reg] + bb1);
      }
    }
  }
}

// ---------------------------------------------------------------------------
// Eval (bf16 store) + totals fused: wave-per-node dot with w_eval, stable
// BCE, plus tot_pos/tot_neg partial sums.  Per-block partials (NO atomics):
// pe[comp][blk]; comp = q*2+m for q in {A,B,posOK,negOK}; comp 8 = tot_pos,
// comp 9 = tot_neg.  loss = pw*A + B assembled in finish (pw factors out).
// ---------------------------------------------------------------------------
__global__ void eval_kernel(const unsigned short* __restrict__ store,
                            const float* __restrict__ pos_cnt, const float* __restrict__ neg_cnt,
                            const float* __restrict__ w_eval, const float* __restrict__ b_eval,
                            float* __restrict__ pe)
{
  __shared__ float part[4][2][5];      // [wave][m][q] ; q=4: m0 slot=sp, m1 slot=sn
  const int t = threadIdx.x, lane = t & 63;
  const int gw = blockIdx.x*(blockDim.x >> 6) + (t >> 6);
  const int nw = gridDim.x*(blockDim.x >> 6);
  float4 wv = *(const float4*)&w_eval[4*lane];          // lanes 0-31 -> m=0, 32-63 -> m=1
  const int m = (lane >= 32) ? 1 : 0;
  const float be = b_eval[m];
  float A = 0.f, B = 0.f, pOK = 0.f, nOK = 0.f, tsum = 0.f;
  for (int n = gw; n < NTOT; n += nw){
    ushort4 v4 = *(const ushort4*)&store[(size_t)n*(MM*DD) + 4*lane];
    float p = bf2f(v4.x)*wv.x + bf2f(v4.y)*wv.y + bf2f(v4.z)*wv.z + bf2f(v4.w)*wv.w;
    #pragma unroll
    for (int s = 1; s < 32; s <<= 1) p += __shfl_xor(p, s, 64);   // reduce within each m-half
    const float val = p + be;
    if ((lane & 31) == 0){
      const float pc = pos_cnt[n], nc = neg_cnt[n];
      const float cnt = pc + nc;
      if (cnt > 0.f){
        float gold = pc / fmaxf(cnt, 1.f);
        float e = log1pf(expf(-fabsf(val)));
        float sp_pos = e + fmaxf(val, 0.f);     // softplus(val)
        float sp_neg = e + fmaxf(-val, 0.f);    // softplus(-val)
        A += cnt * gold * sp_neg;
        B += cnt * (1.f - gold) * sp_pos;
      }
      pOK += (val >= 0.f) ? pc : 0.f;
      nOK += (val <  0.f) ? nc : 0.f;
      tsum += (m == 0) ? pc : nc;               // lane0: tot_pos, lane32: tot_neg
    }
  }
  if ((lane & 31) == 0){
    int wv2 = t >> 6;
    part[wv2][m][0] = A; part[wv2][m][1] = B; part[wv2][m][2] = pOK; part[wv2][m][3] = nOK;
    part[wv2][m][4] = tsum;
  }
  __syncthreads();
  if (t < 10){
    int q = t >> 1, mm = t & 1;                 // q=4 -> comps 8,9 (totals)
    float s = part[0][mm][q] + part[1][mm][q] + part[2][mm][q] + part[3][mm][q];
    pe[t*EBLK + blockIdx.x] = s;
  }
}

// ---------------------------------------------------------------------------
// Finish: reduce 10 eval partial components, compute pw, write 6 outputs.
// ---------------------------------------------------------------------------
__global__ void finish_kernel(const float* __restrict__ pe, float* __restrict__ out)
{
  __shared__ float accv[10];
  const int t = threadIdx.x;             // 256
  {
    int comp = t >> 5, l = t & 31;       // comps 0..7
    float s = 0.f;
    for (int i = 0; i < EBLK/32; ++i) s += pe[comp*EBLK + i*32 + l];
    #pragma unroll
    for (int d = 1; d < 32; d <<= 1) s += __shfl_xor(s, d, 64);
    if (l == 0) accv[comp] = s;
  }
  if (t < 64){                           // comps 8,9
    int comp = 8 + (t >> 5), l = t & 31;
    float s = 0.f;
    for (int i = 0; i < EBLK/32; ++i) s += pe[comp*EBLK + i*32 + l];
    #pragma unroll
    for (int d = 1; d < 32; d <<= 1) s += __shfl_xor(s, d, 64);
    if (l == 0) accv[comp] = s;
  }
  __syncthreads();
  if (t < 2){                            // m = t
    float tp = accv[8], tn = accv[9];
    float pw = (tp > 0.f) ? (tn / fmaxf(tp, 1.f)) : 1.f;   // POS_WEIGHT_EXTRA = 1
    out[t]     = pw*accv[0 + t] + accv[2 + t];
    out[2 + t] = accv[4 + t];
    out[4 + t] = accv[6 + t];
  }
}

// ---------------------------------------------------------------------------
extern "C" void kernel_launch(void* const* d_in, const int* in_sizes, int n_in,
                              void* d_out, int out_size, void* d_ws, size_t ws_size,
                              hipStream_t stream)
{
  const int*   thax_ids   = (const int*)d_in[0];
  const int*   sine_ids   = (const int*)d_in[1];
  const int*   parents    = (const int*)d_in[2];
  const int*   rule_ids   = (const int*)d_in[3];
  const float* pos_cnt    = (const float*)d_in[4];
  const float* neg_cnt    = (const float*)d_in[5];
  const float* thax_table = (const float*)d_in[6];
  const float* sine_w     = (const float*)d_in[7];
  const float* sine_b     = (const float*)d_in[8];
  const float* W1         = (const float*)d_in[9];
  const float* b1         = (const float*)d_in[10];
  const float* W2         = (const float*)d_in[11];
  const float* b2         = (const float*)d_in[12];
  const float* w_eval     = (const float*)d_in[13];
  const float* b_eval     = (const float*)d_in[14];

  char* ws = (char*)d_ws;
  unsigned short* store = (unsigned short*)ws;
  size_t off = (size_t)NTOT*MM*DD*sizeof(unsigned short);   // 71.3 MB
  off = (off + 15) & ~(size_t)15;
  int* chunk_nodes = (int*)(ws + off); off += (size_t)LLV*CHN16*NB*sizeof(int);
  int* chunk_rule  = (int*)(ws + off); off += (size_t)LLV*CHN16*sizeof(int);
  int* nchunks     = (int*)(ws + off); off += (size_t)LLV*sizeof(int);
  float* pe        = (float*)(ws + off); off += (size_t)10*EBLK*sizeof(float);
  off = (off + 15) & ~(size_t)15;
  unsigned short* W1t = (unsigned short*)(ws + off); off += (size_t)MM*RR*256*DD*sizeof(unsigned short);
  unsigned short* W2t = (unsigned short*)(ws + off); off += (size_t)MM*RR*128*DD*sizeof(unsigned short);

  prep_kernel<<<LLV, 256, 0, stream>>>(rule_ids, chunk_nodes, chunk_rule, nchunks);
  convw_kernel<<<(MM*RR*(256+128)*DD + 255)/256, 256, 0, stream>>>(W1, W2, W1t, W2t);
  init_kernel<<<(NN0*MM*DD + 255)/256, 256, 0, stream>>>(thax_ids, sine_ids, thax_table,
                                                         sine_w, sine_b, store);

  for (int l = 0; l < LLV; ++l)
    level_kernel<<<CHN16*2, 256, 0, stream>>>(store, parents, chunk_nodes, chunk_rule,
                                              nchunks, W1t, b1, W2t, b2, l);

  eval_kernel<<<EBLK, 256, 0, stream>>>(store, pos_cnt, neg_cnt, w_eval, b_eval, pe);
  finish_kernel<<<1, 256, 0, stream>>>(pe, (float*)d_out);
}